// Round 6
// baseline (185.227 us; speedup 1.0000x reference)
//
#include <hip/hip_runtime.h>
#include <hip/hip_fp16.h>

#define LOG2E 1.44269504088896340736f
#define DM 1536
#define LL  2048
#define NN  16
#define NCH 64     // chunks per row = lanes per wave
#define CL  32     // LL / NCH

__device__ __forceinline__ float fexp2(float v){ return __builtin_amdgcn_exp2f(v); }
__device__ __forceinline__ float frcp(float v){ return __builtin_amdgcn_rcpf(v); }

__device__ __forceinline__ void load16(const float* __restrict__ p, float* v){
    const float4 a=*(const float4*)p,     b=*(const float4*)(p+4),
                 c=*(const float4*)(p+8), d=*(const float4*)(p+12);
    v[0]=a.x; v[1]=a.y; v[2]=a.z; v[3]=a.w;
    v[4]=b.x; v[5]=b.y; v[6]=b.z; v[7]=b.w;
    v[8]=c.x; v[9]=c.y; v[10]=c.z; v[11]=c.w;
    v[12]=d.x; v[13]=d.y; v[14]=d.z; v[15]=d.w;
}

__device__ __forceinline__ float packdx(float d, float x){
    unsigned u = (unsigned)__half_as_ushort(__float2half_rn(d))
               | ((unsigned)__half_as_ushort(__float2half_rn(x)) << 16);
    return __uint_as_float(u);
}
__device__ __forceinline__ void unpackdx(float f, float& d, float& x){
    const unsigned u = __float_as_uint(f);
    d = __half2float(__ushort_as_half((unsigned short)(u & 0xffffu)));
    x = __half2float(__ushort_as_half((unsigned short)(u >> 16)));
}

// B,C: [b][n][t] -> Bt[((b*32 + (t&31))*64 + (t>>5))*16 + n]
// Input-indexed: coalesced float4 reads, scattered dword writes (fire&forget).
__global__ __launch_bounds__(256) void transpose_bc(
        const float* __restrict__ Bm, const float* __restrict__ Cm,
        float* __restrict__ Bt, float* __restrict__ Ct){
    const int q  = blockIdx.x*256 + threadIdx.x;   // 16384 float4 quads
    const int t0 = (q & 511) << 2;
    const int n  = (q >> 9) & 15;
    const int b  = q >> 13;
    const long i = (long)(b*NN + n)*LL + t0;
    const float4 bv = *(const float4*)(Bm + i);
    const float4 cv = *(const float4*)(Cm + i);
    const float bb[4]={bv.x,bv.y,bv.z,bv.w}, cc[4]={cv.x,cv.y,cv.z,cv.w};
#pragma unroll
    for (int j=0;j<4;++j){
        const int t = t0 + j;
        const int o = ((b*CL + (t&31))*NCH + (t>>5))*NN + n;
        Bt[o] = bb[j];
        Ct[o] = cc[j];
    }
}

// Block = 4 waves, wave = one (b,d) row; lane = chunk (64 x 32 steps);
// thread owns all 16 states. (delta,x) staged in LDS as packed half2 with
// XOR swizzle slot(r,c)=r*64+(c^r) (<=2-way banking everywhere = free).
// 32 KB LDS/block + launch_bounds(256,3) -> 3 blocks/CU, grid 768 = all
// blocks co-resident (no tail). B/C slab loads software-pipelined (dist 1).
__global__ __launch_bounds__(256, 3) void ssm_scan(
    const float* __restrict__ x, const float* __restrict__ delta,
    const float* __restrict__ A, const float* __restrict__ Dv,
    const float* __restrict__ z, const float* __restrict__ Bt,
    const float* __restrict__ Ct, float* __restrict__ out)
{
    __shared__ float sdx[4][CL*64];  // packed half2{delta,x}; fp32 (y+x*D) after phase 3

    const int lane = threadIdx.x & 63;
    const int w    = threadIdx.x >> 6;
    const int row  = blockIdx.x*4 + w;           // b*DM + d
    const int b    = (row >= DM) ? 1 : 0;
    const int d    = row - b*DM;
    float* sw = sdx[w];

    const long base = (long)row*LL;
    const float* gd = delta + base;
    const float* gx = x + base;

    // ---- stage packed (delta,x): coalesced float4 reads, 2-way LDS writes
    for (int k=0;k<LL;k+=256){
        const int t0 = k + lane*4;
        const float4 dv = *(const float4*)(gd + t0);
        const float4 xv = *(const float4*)(gx + t0);
        const float dd[4]={dv.x,dv.y,dv.z,dv.w};
        const float xx[4]={xv.x,xv.y,xv.z,xv.w};
#pragma unroll
        for (int j=0;j<4;++j){
            const int t = t0 + j, r = t & 31, c = t >> 5;
            sw[r*64 + (c^r)] = packdx(dd[j], xx[j]);
        }
    }

    float A2[NN];
#pragma unroll
    for (int n=0;n<NN;++n) A2[n] = A[d*NN+n] * LOG2E;   // exp(dA)=exp2(d*A2)

    const float* bq = Bt + (long)b*(CL*NCH*NN) + lane*NN;  // + r*1024 per step
    const float* cq = Ct + (long)b*(CL*NCH*NN) + lane*NN;

    // ---- phase 1: local scan h0=0 -> G; P = exp2(A2 * sum(delta))
    float G[NN];
#pragma unroll
    for (int n=0;n<NN;++n) G[n] = 0.f;
    float dsum = 0.f;
    float bb[NN];
    load16(bq, bb);
#pragma unroll 2
    for (int r=0;r<CL;++r){
        float nb[NN];
        if (r+1 < CL) load16(bq + (r+1)*(NCH*NN), nb);
        float d_r, x_r;
        unpackdx(sw[r*64 + (lane^r)], d_r, x_r);
        dsum += d_r;
        const float dx = d_r * x_r;
#pragma unroll
        for (int n=0;n<NN;++n){
            const float e = fexp2(d_r*A2[n]);
            G[n] = __builtin_fmaf(e, G[n], bb[n]*dx);
        }
        if (r+1 < CL){
#pragma unroll
            for (int n=0;n<NN;++n) bb[n] = nb[n];
        }
    }
    float P[NN];
#pragma unroll
    for (int n=0;n<NN;++n) P[n] = fexp2(dsum*A2[n]);

    // ---- phase 2: inclusive Kogge-Stone wave scan over chunks, then shift
#pragma unroll
    for (int s=1;s<64;s<<=1){
#pragma unroll
        for (int n=0;n<NN;++n){
            const float pl = __shfl_up(P[n], s);
            const float gl = __shfl_up(G[n], s);
            if (lane >= s){
                G[n] = __builtin_fmaf(P[n], gl, G[n]);
                P[n] *= pl;
            }
        }
    }
    float h[NN];
#pragma unroll
    for (int n=0;n<NN;++n){
        const float gp = __shfl_up(G[n], 1);
        h[n] = (lane==0) ? 0.f : gp;
    }

    // ---- phase 3: re-scan with true h_start; stash (y + x*D) into LDS slot
    const float Dd = Dv[d];
    float cc[NN];
    load16(bq, bb);
    load16(cq, cc);
#pragma unroll 2
    for (int r=0;r<CL;++r){
        float nb[NN], nc[NN];
        if (r+1 < CL){
            load16(bq + (r+1)*(NCH*NN), nb);
            load16(cq + (r+1)*(NCH*NN), nc);
        }
        const int a = r*64 + (lane ^ r);
        float d_r, x_r;
        unpackdx(sw[a], d_r, x_r);
        const float dx = d_r * x_r;
        float y0=0.f, y1=0.f, y2=0.f, y3=0.f;
#pragma unroll
        for (int n=0;n<NN;n+=4){
            const float e0=fexp2(d_r*A2[n+0]);
            h[n+0]=__builtin_fmaf(e0,h[n+0],bb[n+0]*dx); y0=__builtin_fmaf(h[n+0],cc[n+0],y0);
            const float e1=fexp2(d_r*A2[n+1]);
            h[n+1]=__builtin_fmaf(e1,h[n+1],bb[n+1]*dx); y1=__builtin_fmaf(h[n+1],cc[n+1],y1);
            const float e2=fexp2(d_r*A2[n+2]);
            h[n+2]=__builtin_fmaf(e2,h[n+2],bb[n+2]*dx); y2=__builtin_fmaf(h[n+2],cc[n+2],y2);
            const float e3=fexp2(d_r*A2[n+3]);
            h[n+3]=__builtin_fmaf(e3,h[n+3],bb[n+3]*dx); y3=__builtin_fmaf(h[n+3],cc[n+3],y3);
        }
        const float y = (y0+y1)+(y2+y3);
        sw[a] = __builtin_fmaf(x_r, Dd, y);      // (y + x*D), silu applied later
        if (r+1 < CL){
#pragma unroll
            for (int n=0;n<NN;++n){ bb[n]=nb[n]; cc[n]=nc[n]; }
        }
    }

    // ---- epilogue: stream z once, fully coalesced float4 in/out
    const float* gz = z + base;
    float* go = out + base;
    for (int k=0;k<LL;k+=256){
        const int t0 = k + lane*4;
        const float4 zv = *(const float4*)(gz + t0);
        const float zz[4]={zv.x,zv.y,zv.z,zv.w};
        float o[4];
#pragma unroll
        for (int j=0;j<4;++j){
            const int t = t0 + j, r = t & 31, c = t >> 5;
            const float yd = sw[r*64 + (c^r)];
            const float sig = frcp(1.f + fexp2(-zz[j]*LOG2E));
            o[j] = yd * (zz[j]*sig);
        }
        float4 o4 = {o[0],o[1],o[2],o[3]};
        *(float4*)(go + t0) = o4;
    }
}

extern "C" void kernel_launch(void* const* d_in, const int* in_sizes, int n_in,
                              void* d_out, int out_size, void* d_ws, size_t ws_size,
                              hipStream_t stream) {
    const float* x     = (const float*)d_in[0];
    const float* delta = (const float*)d_in[1];
    const float* A     = (const float*)d_in[2];
    const float* B     = (const float*)d_in[3];
    const float* C     = (const float*)d_in[4];
    const float* Dv    = (const float*)d_in[5];
    const float* z     = (const float*)d_in[6];
    float* out = (float*)d_out;

    float* Bt = (float*)d_ws;                  // 65536 floats = 256 KB
    float* Ct = Bt + 2*LL*NN;                  // next 256 KB

    transpose_bc<<<dim3(64), dim3(256), 0, stream>>>(B, C, Bt, Ct);
    ssm_scan<<<dim3((2*DM)/4), dim3(256), 0, stream>>>(x, delta, A, Dv, z, Bt, Ct, out);
}